// Round 13
// baseline (151.569 us; speedup 1.0000x reference)
//
#include <hip/hip_runtime.h>
#include <math.h>

#define BB 128
#define LL 720
#define CC 321
#define HH 128
#define PP 336
#define MM 512
#define NSTEP 23   // K-steps of 32 (736 = 23*32, zero-padded past 720)

typedef __attribute__((ext_vector_type(8))) short bf16x8;
typedef __attribute__((ext_vector_type(4))) float f32x4;

__device__ __forceinline__ short f2bf(float x) {
  unsigned u = __builtin_bit_cast(unsigned, x);
  u = (u + 0x7FFFu + ((u >> 16) & 1u)) >> 16;
  return (short)u;
}

// packed position of k-within-32-group: fragment lg*8 + half*4 + j
__device__ __forceinline__ int packpos(int kw) {
  return ((kw & 15) >> 2) * 8 + (kw >> 4) * 4 + (kw & 3);
}

// async global->LDS, 16 bytes per lane; lds ptr must be wave-uniform base
__device__ __forceinline__ void gload_lds16(const short* g, short* l) {
  __builtin_amdgcn_global_load_lds(
      (const __attribute__((address_space(1))) unsigned int*)g,
      (__attribute__((address_space(3))) unsigned int*)l, 16, 0, 0);
}

#define VMCNT8 asm volatile("s_waitcnt vmcnt(8)" ::: "memory")
#define VMCNT0 asm volatile("s_waitcnt vmcnt(0)" ::: "memory")
#define LGKM0 asm volatile("s_waitcnt lgkmcnt(0)" ::: "memory")
#define RAWBAR                                \
  do {                                        \
    __builtin_amdgcn_sched_barrier(0);        \
    __builtin_amdgcn_s_barrier();             \
    __builtin_amdgcn_sched_barrier(0);        \
    asm volatile("" ::: "memory");            \
  } while (0)

// ---------------------------------------------------------------------------
// Kernel 1 (v5): smeared weights -> W image for gemm1 (BK=32), unchanged r12.
// ---------------------------------------------------------------------------
__global__ void weff_kernel(const float* __restrict__ Ws1,
                            const float* __restrict__ Wt1,
                            short* __restrict__ wimg) {
  int idx = blockIdx.x * 256 + threadIdx.x;
  if (idx >= HH * NSTEP * 32) return;
  int j = idx % (NSTEP * 32), h = idx / (NSTEP * 32);
  int s = j >> 5, kw = j & 31;
  int half = kw >> 4, lg = (kw >> 2) & 3, jj = kw & 3;
  size_t base = ((size_t)(s * 128 + h)) * 64 + half * 4 + jj;
  int slotS = (0 + lg) ^ (h & 7);
  int slotT = (4 + lg) ^ (h & 7);
  if (j >= LL) {
    wimg[base + slotS * 8] = 0;
    wimg[base + slotT * 8] = 0;
    return;
  }
  float ss = 0.f, st = 0.f;
  if (j == 0) {
    for (int l = 0; l <= 12; ++l) {
      float w = 13.f - (float)l;
      ss += w * Ws1[h * LL + l];
      st += w * Wt1[h * LL + l];
    }
  } else if (j == LL - 1) {
    for (int d = 0; d <= 12; ++d) {
      float w = 13.f - (float)d;
      ss += w * Ws1[h * LL + LL - 1 - d];
      st += w * Wt1[h * LL + LL - 1 - d];
    }
  } else {
    int lo = j - 12 < 0 ? 0 : j - 12;
    int hi = j + 12 > LL - 1 ? LL - 1 : j + 12;
    for (int l = lo; l <= hi; ++l) {
      ss += Ws1[h * LL + l];
      st += Wt1[h * LL + l];
    }
  }
  ss *= (1.f / 25.f);
  st *= (1.f / 25.f);
  wimg[base + slotS * 8] = f2bf(Ws1[h * LL + j] - ss);
  wimg[base + slotT * 8] = f2bf(st);
}

// ---------------------------------------------------------------------------
// Kernel 1b: staged mem images for memenh (unchanged).
// ---------------------------------------------------------------------------
__global__ void memstage_kernel(const float* __restrict__ memS,
                                const float* __restrict__ memT,
                                short* __restrict__ stgS,
                                short* __restrict__ stgT) {
  int e = blockIdx.x * 256 + threadIdx.x;  // 0..32767
  int br = e >> 14;
  int s = e & 16383;
  const float* src = br ? memT : memS;
  short* dst = br ? stgT : stgS;
  int tt = s >> 11;                        // tile 0..7
  int c = s & 2047;
  int row = c >> 4, slot = c & 15;
  int sp = slot ^ (row & 7);
  int k = sp >> 2, lg = sp & 3;
  int ft = tt >> 1;
  short out[8];
  if ((tt & 1) == 0) {
    const float* r0 = src + (size_t)(ft * 128 + row) * 128 + k * 32 + lg * 4;
#pragma unroll
    for (int j = 0; j < 4; ++j) {
      out[j] = f2bf(r0[j]);
      out[j + 4] = f2bf(r0[16 + j]);
    }
  } else {
    int fbase = ft * 128 + k * 32 + lg * 4;
#pragma unroll
    for (int j = 0; j < 4; ++j) {
      out[j] = f2bf(src[(size_t)(fbase + j) * 128 + row]);
      out[j + 4] = f2bf(src[(size_t)(fbase + 16 + j) * 128 + row]);
    }
  }
  short4 a = make_short4(out[0], out[1], out[2], out[3]);
  short4 b = make_short4(out[4], out[5], out[6], out[7]);
  *(short4*)&dst[(size_t)s * 8] = a;
  *(short4*)&dst[(size_t)s * 8 + 4] = b;
}

// ---------------------------------------------------------------------------
// Kernel 1c: W2cat bf16 [336][512], fragment-packed per 32-group, + bias sum.
// ---------------------------------------------------------------------------
__global__ void w2cvt_kernel(const float* __restrict__ Ws2,
                             const float* __restrict__ Wt2,
                             const float* __restrict__ bs2,
                             const float* __restrict__ bt2,
                             short* __restrict__ W2b, float* __restrict__ b2) {
  int i = blockIdx.x * 256 + threadIdx.x;
  if (i < PP) b2[i] = bs2[i] + bt2[i];
  if (i >= PP * 512) return;
  int p = i >> 9, k = i & 511;
  float v = (k < 256) ? Ws2[p * 256 + k] : Wt2[p * 256 + (k - 256)];
  W2b[p * 512 + (k >> 5) * 32 + packpos(k & 31)] = f2bf(v);
}

// ---------------------------------------------------------------------------
// Kernel 2 (v9): MFMA dual-branch GEMM1 + sigmoid — T4 counted-vmcnt pipeline.
//   Same tile/layout as v8 (32n x 128h x 2br, BK=32, grid 1284) but:
//   - triple-buffered W (gload_lds) and x (reg->ds_write), depth-2 prefetch
//   - raw s_barrier with counted vmcnt(8) (never 0 in steady state): the
//     next-next batch stays in flight across the barrier, so no per-step
//     latency round trip (the 2-phase drain was the 7-round invariant).
// ---------------------------------------------------------------------------
__global__ __launch_bounds__(256) void gemm1_mfma(
    const float* __restrict__ x, const short* __restrict__ wimg,
    const float* __restrict__ bs1, const float* __restrict__ bt1,
    short* __restrict__ r2s, short* __restrict__ r2t) {
  __shared__ __align__(16) short wbuf[3][8192];  // 48 KB
  __shared__ __align__(16) short xbuf[3][1024];  // 6 KB
  int tid = threadIdx.x;
  int w = tid >> 6, l = tid & 63, lr = l & 15, lg = l >> 4;
  int br = w >> 1, hb = (w & 1) * 64;
  int nb = blockIdx.x * 32;  // 41088 = 1284*32 exact

  // x gather mapping: thread = (krow 0..7, xcol 0..31); per wave: 4 dword loads
  int xcol = tid & 31, krow = tid >> 5;
  int xn = nb + xcol;
  int xb_ = xn / CC, xc_ = xn - xb_ * CC;
  const float* xptr = x + (size_t)xb_ * (LL * CC) + xc_;
  int xrow = xcol >> 1;
  int xslot = ((xcol & 1) * 4 + (krow & 3)) ^ (xrow & 7);
  int xdst = xrow * 64 + xslot * 8 + (krow >> 2) * 4;

  // W staging: wave w stages shorts [w*2048, +2048) of each step image: 4 inst
  const short* wsrc = wimg + (size_t)w * 2048 + l * 8;

  f32x4 acc[4][2];  // [ht][n-grp]
#pragma unroll
  for (int i = 0; i < 4; ++i)
#pragma unroll
    for (int g = 0; g < 2; ++g) acc[i][g] = (f32x4){0.f, 0.f, 0.f, 0.f};

  float xf0[4], xfA[4], xfB[4];

  // ---- prologue: issue batches 0 and 1; commit x(0); wait W(0) ----
#pragma unroll
  for (int j = 0; j < 4; ++j) xf0[j] = xptr[(size_t)(krow * 4 + j) * CC];
#pragma unroll
  for (int i = 0; i < 4; ++i)
    gload_lds16(wsrc + i * 512, &wbuf[0][w * 2048 + i * 512]);
#pragma unroll
  for (int j = 0; j < 4; ++j)
    xfA[j] = xptr[(size_t)(32 + krow * 4 + j) * CC];
#pragma unroll
  for (int i = 0; i < 4; ++i)
    gload_lds16(wsrc + 8192 + i * 512, &wbuf[1][w * 2048 + i * 512]);
  {
    short4 v = make_short4(f2bf(xf0[0]), f2bf(xf0[1]), f2bf(xf0[2]),
                           f2bf(xf0[3]));  // compiler auto-waits xf0 loads
    *(short4*)&xbuf[0][xdst] = v;
  }
  VMCNT8;  // W(0) complete (batch 1's 8 still outstanding)
  LGKM0;
  RAWBAR;

  int bc = 0, bn = 1, bi = 2;
  for (int s = 0; s < NSTEP; ++s) {
    // issue batch s+2 (x -> regs, W -> wbuf[bi])
    if (s < NSTEP - 2) {
      int kb = (s + 2) * 32 + krow * 4;
#pragma unroll
      for (int j = 0; j < 4; ++j) {
        int k = kb + j;
        xfB[j] = (k < LL) ? xptr[(size_t)k * CC] : 0.f;
      }
      const short* ws = wsrc + (size_t)(s + 2) * 8192;
#pragma unroll
      for (int i = 0; i < 4; ++i)
        gload_lds16(ws + i * 512, &wbuf[bi][w * 2048 + i * 512]);
    }

    // compute step s from wbuf[bc], xbuf[bc]
    {
      const short* tw = &wbuf[bc][0];
      const short* tx = &xbuf[bc][0];
      bf16x8 bx[2];
#pragma unroll
      for (int g = 0; g < 2; ++g) {
        int cc = g * 16 + lr;
        int row = cc >> 1;
        int slot = ((cc & 1) * 4 + lg) ^ (row & 7);
        bx[g] = *(const bf16x8*)&tx[row * 64 + slot * 8];
      }
#pragma unroll
      for (int ht = 0; ht < 4; ++ht) {
        int h = hb + ht * 16 + lr;
        int slot = (br * 4 + lg) ^ (h & 7);
        bf16x8 a = *(const bf16x8*)&tw[h * 64 + slot * 8];
        acc[ht][0] = __builtin_amdgcn_mfma_f32_16x16x32_bf16(a, bx[0],
                                                             acc[ht][0], 0, 0, 0);
        acc[ht][1] = __builtin_amdgcn_mfma_f32_16x16x32_bf16(a, bx[1],
                                                             acc[ht][1], 0, 0, 0);
      }
    }

    if (s < NSTEP - 1) {
      // commit x(s+1) to xbuf[bn] (compiler auto-waits xfA's own loads)
      short4 v = make_short4(f2bf(xfA[0]), f2bf(xfA[1]), f2bf(xfA[2]),
                             f2bf(xfA[3]));
      *(short4*)&xbuf[bn][xdst] = v;
      if (s < NSTEP - 2) {
        VMCNT8;  // W(s+1) complete; batch(s+2) stays in flight
      } else {
        VMCNT0;  // tail: drain last W
      }
      LGKM0;
      RAWBAR;
#pragma unroll
      for (int j = 0; j < 4; ++j) xfA[j] = xfB[j];
    }
    int t = bc;
    bc = bn;
    bn = bi;
    bi = t;
  }

  // epilogue: sigmoid -> PACKED bf16 R at shorts [128..255] of each r2 row
  const float* bias = br ? bt1 : bs1;
  short* r2 = br ? r2t : r2s;
#pragma unroll
  for (int ht = 0; ht < 4; ++ht) {
    int h0 = hb + ht * 16 + lg * 4;
    int dst = (h0 >> 5) * 32 + lg * 8 + ((h0 >> 4) & 1) * 4;
    float4 bi4 = *(const float4*)&bias[h0];
    const float* pb = &bi4.x;
#pragma unroll
    for (int g = 0; g < 2; ++g) {
      int n = nb + g * 16 + lr;
      short4 v;
      short* pv = &v.x;
#pragma unroll
      for (int j = 0; j < 4; ++j)
        pv[j] = f2bf(1.f / (1.f + __expf(-(acc[ht][g][j] + pb[j]))));
      *(short4*)&r2[(size_t)n * 256 + 128 + dst] = v;
    }
  }
}

// ---------------------------------------------------------------------------
// Kernel 3: pipelined MFMA memory-enhance (unchanged).
// ---------------------------------------------------------------------------
__global__ __launch_bounds__(256) void memenh_mfma(
    const short* __restrict__ stgS, const short* __restrict__ stgT,
    short* __restrict__ r2s, short* __restrict__ r2t) {
  int br = blockIdx.y;
  const short* stg = br ? stgT : stgS;
  short* r2 = br ? r2t : r2s;

  __shared__ __align__(16) short buf[2][16384];  // 64 KB
  int tid = threadIdx.x;
  int l = tid & 63, lr = l & 15, lg = l >> 4;
  int wbase = tid & 192;
  int n = blockIdx.x * 64 + (tid >> 6) * 16 + lr;

  bf16x8 brag[4];
  {
    const short* rb = r2 + (size_t)n * 256 + 128;
#pragma unroll
    for (int k = 0; k < 4; ++k)
      brag[k] = *(const bf16x8*)&rb[k * 32 + lg * 8];
  }

#define STAGE(t, bsel)                                                        \
  {                                                                           \
    const short* g = stg + (size_t)(t)*16384;                                 \
    _Pragma("unroll") for (int i = 0; i < 8; ++i) {                           \
      gload_lds16(g + (size_t)(i * 256 + tid) * 8,                            \
                  &buf[bsel][(i * 256 + wbase) * 8]);                         \
    }                                                                         \
  }

  STAGE(0, 0);
  __syncthreads();

  f32x4 accO[8];
#pragma unroll
  for (int i = 0; i < 8; ++i) accO[i] = (f32x4){0.f, 0.f, 0.f, 0.f};
  bf16x8 pb[4];
  float ssum = 0.f;
  int cur = 0;

#pragma unroll
  for (int t = 0; t < 8; ++t) {
    if (t < 7) STAGE(t + 1, cur ^ 1);
    const short* tb = &buf[cur][0];
    if ((t & 1) == 0) {
      f32x4 sc[8];
#pragma unroll
      for (int ft16 = 0; ft16 < 8; ++ft16) {
        f32x4 a = {0.f, 0.f, 0.f, 0.f};
#pragma unroll
        for (int k = 0; k < 4; ++k) {
          int row = ft16 * 16 + lr;
          int slot = (4 * k + lg) ^ (row & 7);
          bf16x8 af = *(const bf16x8*)&tb[row * 128 + slot * 8];
          a = __builtin_amdgcn_mfma_f32_16x16x32_bf16(af, brag[k], a, 0, 0, 0);
        }
        sc[ft16] = a;
      }
#pragma unroll
      for (int i = 0; i < 8; ++i) {
        f32x4 v = sc[i];
#pragma unroll
        for (int j = 0; j < 4; ++j) {
          float e = __expf(v[j]);
          v[j] = e;
          ssum += e;
        }
        sc[i] = v;
      }
#pragma unroll
      for (int t4 = 0; t4 < 4; ++t4) {
        f32x4 e0 = sc[2 * t4], e1 = sc[2 * t4 + 1];
        bf16x8 f;
        f[0] = f2bf(e0[0]); f[1] = f2bf(e0[1]);
        f[2] = f2bf(e0[2]); f[3] = f2bf(e0[3]);
        f[4] = f2bf(e1[0]); f[5] = f2bf(e1[1]);
        f[6] = f2bf(e1[2]); f[7] = f2bf(e1[3]);
        pb[t4] = f;
      }
    } else {
#pragma unroll
      for (int dt = 0; dt < 8; ++dt) {
#pragma unroll
        for (int k = 0; k < 4; ++k) {
          int row = dt * 16 + lr;
          int slot = (4 * k + lg) ^ (row & 7);
          bf16x8 af = *(const bf16x8*)&tb[row * 128 + slot * 8];
          accO[dt] =
              __builtin_amdgcn_mfma_f32_16x16x32_bf16(af, pb[k], accO[dt], 0, 0, 0);
        }
      }
    }
    __syncthreads();
    cur ^= 1;
  }
#undef STAGE

  ssum += __shfl_xor(ssum, 16);
  ssum += __shfl_xor(ssum, 32);
  float inv = 1.f / ssum;
  short* rowO = r2 + (size_t)n * 256;
#pragma unroll
  for (int dt = 0; dt < 8; ++dt) {
    short4 o;
    o.x = f2bf(accO[dt][0] * inv);
    o.y = f2bf(accO[dt][1] * inv);
    o.z = f2bf(accO[dt][2] * inv);
    o.w = f2bf(accO[dt][3] * inv);
    *(short4*)&rowO[(dt >> 1) * 32 + lg * 8 + (dt & 1) * 4] = o;
  }
}

// ---------------------------------------------------------------------------
// Kernel 4: MFMA GEMM2 (bf16, K=512 concat, packed operands) + bias +
//   transposed store (unchanged).
// ---------------------------------------------------------------------------
__global__ __launch_bounds__(512) void gemm2_mfma(
    const short* __restrict__ r2s, const short* __restrict__ r2t,
    const short* __restrict__ W2b,  // [336][512] bf16 packed
    const float* __restrict__ b2,   // [336]
    float* __restrict__ out) {
  __shared__ __align__(16) short w2lds[2][112 * 40];  // 17.9 KB
  int tid = threadIdx.x;
  int w = tid >> 6, l = tid & 63, lr = l & 15, lg = l >> 4;
  int p0 = blockIdx.y * 112;
  int n = blockIdx.x * 128 + w * 16 + lr;
  int b = n / CC, c = n - b * CC;
  const short* rs = r2s + (size_t)n * 256;
  const short* rt = r2t + (size_t)n * 256;

  bool dostage = tid < 448;
  int row = tid >> 2, q = tid & 3;
  const short* gW = W2b + (size_t)(p0 + row) * 512 + q * 8;
  int doff = row * 40 + q * 8;

  f32x4 acc[7];
#pragma unroll
  for (int i = 0; i < 7; ++i) acc[i] = (f32x4){0.f, 0.f, 0.f, 0.f};

  if (dostage) *(int4*)&w2lds[0][doff] = *(const int4*)gW;
  __syncthreads();

  int cur = 0;
  for (int step = 0; step < 16; ++step) {
    int k0 = step * 32;
    const short* rrow = ((k0 < 256) ? rs : rt) + (k0 & 255);
    bf16x8 bfr = *(const bf16x8*)&rrow[lg * 8];
    int4 nxt = {0, 0, 0, 0};
    if (step < 15 && dostage) nxt = *(const int4*)(gW + (step + 1) * 32);
    const short* tw = &w2lds[cur][0];
#pragma unroll
    for (int pt = 0; pt < 7; ++pt) {
      bf16x8 a = *(const bf16x8*)&tw[(pt * 16 + lr) * 40 + lg * 8];
      acc[pt] = __builtin_amdgcn_mfma_f32_16x16x32_bf16(a, bfr, acc[pt], 0, 0, 0);
    }
    if (step < 15 && dostage) *(int4*)&w2lds[cur ^ 1][doff] = nxt;
    __syncthreads();
    cur ^= 1;
  }

  size_t obase = (size_t)b * ((size_t)PP * CC) + c;
#pragma unroll
  for (int pt = 0; pt < 7; ++pt) {
    int p = p0 + pt * 16 + lg * 4;
    float4 bias = *(const float4*)&b2[p];
    const float* pb = &bias.x;
#pragma unroll
    for (int j = 0; j < 4; ++j) {
      out[obase + (size_t)(p + j) * CC] = acc[pt][j] + pb[j];
    }
  }
}

// ---------------------------------------------------------------------------
extern "C" void kernel_launch(void* const* d_in, const int* in_sizes, int n_in,
                              void* d_out, int out_size, void* d_ws, size_t ws_size,
                              hipStream_t stream) {
  const float* x    = (const float*)d_in[0];
  const float* Ws1  = (const float*)d_in[1];
  const float* bs1  = (const float*)d_in[2];
  const float* Ws2  = (const float*)d_in[3];
  const float* bs2  = (const float*)d_in[4];
  const float* Wt1  = (const float*)d_in[5];
  const float* bt1  = (const float*)d_in[6];
  const float* Wt2  = (const float*)d_in[7];
  const float* bt2  = (const float*)d_in[8];
  const float* memS = (const float*)d_in[9];
  const float* memT = (const float*)d_in[10];
  float* out = (float*)d_out;

  const size_t N = (size_t)BB * CC;          // 41088
  short* r2s  = (short*)d_ws;                // [N][256] bf16 packed: [O | R]
  short* r2t  = r2s + N * 256;
  short* wimg = r2t + N * 256;               // [23][128][128B] = 368 KB
  short* stgS = wimg + (size_t)NSTEP * 128 * 64;
  short* stgT = stgS + (size_t)16384 * 8;
  short* W2b  = stgT + (size_t)16384 * 8;    // [336][512] bf16 packed
  float* b2   = (float*)(W2b + (size_t)PP * 512);

  // 1. precompute weights / staged conversions
  weff_kernel<<<(HH * NSTEP * 32 + 255) / 256, 256, 0, stream>>>(Ws1, Wt1, wimg);
  memstage_kernel<<<128, 256, 0, stream>>>(memS, memT, stgS, stgT);
  w2cvt_kernel<<<(PP * 512) / 256, 256, 0, stream>>>(Ws2, Wt2, bs2, bt2, W2b, b2);

  // 2. MFMA GEMM1 + sigmoid (both branches), T4 counted-vmcnt, grid 1284
  gemm1_mfma<<<1284, 256, 0, stream>>>(x, wimg, bs1, bt1, r2s, r2t);

  // 3. pipelined MFMA memory enhance, both branches in one dispatch
  dim3 g3(642, 2);
  memenh_mfma<<<g3, 256, 0, stream>>>(stgS, stgT, r2s, r2t);

  // 4. MFMA GEMM2 + bias + transposed store
  dim3 g2(321, 3);
  gemm2_mfma<<<g2, 512, 0, stream>>>(r2s, r2t, W2b, b2, out);
}